// Round 3
// baseline (1212.782 us; speedup 1.0000x reference)
//
#include <hip/hip_runtime.h>
#include <hip/hip_bf16.h>

#define F_IN 512
#define HID 16
#define NCLS 64
#define NBUCK_MAX 512     // LDS sizing; actual nbuck = ceil(N/256) = 391
#define EPB 8192          // edges per block in hist/partition

// ---------------------------------------------------------------------------
// K1: h0 = relu(x @ W1 + b1), inv0 = 1/max(||h0||,eps)
// 4 rows per wave-iteration. Lane owns k-slices {4*lane..4*lane+3} and
// {256+4*lane..+3}. W1 chunk loaded once per kk, reused across 4 rows.
// Value-halving shuffle reduction: 63 shuffles / 4 rows, coalesced store.
// ---------------------------------------------------------------------------
__global__ __launch_bounds__(256, 3) void gemm1_kernel(
    const float* __restrict__ x, const float* __restrict__ W1,
    const float* __restrict__ b1, float* __restrict__ h0,
    float* __restrict__ inv0, int N, int totalWaves)
{
    int wid  = (blockIdx.x * blockDim.x + threadIdx.x) >> 6;
    int lane = threadIdx.x & 63;
    float bias = b1[lane & 15];
    bool b5 = (lane & 32) != 0;
    bool b4 = (lane & 16) != 0;
    bool b3 = (lane & 8)  != 0;
    bool b2 = (lane & 4)  != 0;
    bool b1b = (lane & 2) != 0;
    bool b0 = (lane & 1)  != 0;

    for (int rb = wid * 4; rb < N; rb += totalWaves * 4) {
        int nr = N - rb;  // rows valid this group (>=1)
        float xa[4][4], xb[4][4];
#pragma unroll
        for (int r = 0; r < 4; ++r) {
            int row = rb + ((r < nr) ? r : 0);
            const float4* xp = (const float4*)(x + (size_t)row * F_IN);
            float4 ta = xp[lane];       // k = 4*lane..+3
            float4 tb = xp[64 + lane];  // k = 256+4*lane..+3
            xa[r][0] = ta.x; xa[r][1] = ta.y; xa[r][2] = ta.z; xa[r][3] = ta.w;
            xb[r][0] = tb.x; xb[r][1] = tb.y; xb[r][2] = tb.z; xb[r][3] = tb.w;
        }

        float acc[4][16];
#pragma unroll
        for (int r = 0; r < 4; ++r)
#pragma unroll
            for (int i = 0; i < 16; ++i) acc[r][i] = 0.f;

#pragma unroll
        for (int kk = 0; kk < 4; ++kk) {
            const float4* w1p = (const float4*)(W1 + (size_t)(4 * lane + kk) * HID);
            const float4* w2p = (const float4*)(W1 + (size_t)(256 + 4 * lane + kk) * HID);
            float wA[16], wB[16];
#pragma unroll
            for (int jj = 0; jj < 4; ++jj) {
                float4 t = w1p[jj];
                wA[jj*4+0] = t.x; wA[jj*4+1] = t.y; wA[jj*4+2] = t.z; wA[jj*4+3] = t.w;
                float4 u = w2p[jj];
                wB[jj*4+0] = u.x; wB[jj*4+1] = u.y; wB[jj*4+2] = u.z; wB[jj*4+3] = u.w;
            }
#pragma unroll
            for (int r = 0; r < 4; ++r) {
                float va = xa[r][kk], vb = xb[r][kk];
#pragma unroll
                for (int i = 0; i < 16; ++i)
                    acc[r][i] += va * wA[i] + vb * wB[i];
            }
        }

        // ---- reduction ----
        // step 32: keep row-pair {2*b5, 2*b5+1}
        float v01[16], v23[16];
#pragma unroll
        for (int i = 0; i < 16; ++i) {
            float k0 = b5 ? acc[2][i] : acc[0][i];
            float s0 = b5 ? acc[0][i] : acc[2][i];
            v01[i] = k0 + __shfl_xor(s0, 32);
            float k1 = b5 ? acc[3][i] : acc[1][i];
            float s1 = b5 ? acc[1][i] : acc[3][i];
            v23[i] = k1 + __shfl_xor(s1, 32);
        }
        // step 16: keep row g = 2*b5 + b4  (= lane>>4)
        float v[16];
#pragma unroll
        for (int i = 0; i < 16; ++i) {
            float k = b4 ? v23[i] : v01[i];
            float s = b4 ? v01[i] : v23[i];
            v[i] = k + __shfl_xor(s, 16);
        }
        // halving steps: land value j on lane with (lane&15)==j
#pragma unroll
        for (int i = 0; i < 8; ++i) {
            float k = b3 ? v[i+8] : v[i];
            float s = b3 ? v[i] : v[i+8];
            v[i] = k + __shfl_xor(s, 8);
        }
#pragma unroll
        for (int i = 0; i < 4; ++i) {
            float k = b2 ? v[i+4] : v[i];
            float s = b2 ? v[i] : v[i+4];
            v[i] = k + __shfl_xor(s, 4);
        }
#pragma unroll
        for (int i = 0; i < 2; ++i) {
            float k = b1b ? v[i+2] : v[i];
            float s = b1b ? v[i] : v[i+2];
            v[i] = k + __shfl_xor(s, 2);
        }
        {
            float k = b0 ? v[1] : v[0];
            float s = b0 ? v[0] : v[1];
            v[0] = k + __shfl_xor(s, 1);
        }

        float val = fmaxf(v[0] + bias, 0.f);
        int g = lane >> 4;
        int row = rb + g;
        if (row < N) h0[(size_t)rb * HID + lane] = val;  // coalesced 256B

        float q = val * val;
        q += __shfl_xor(q, 1);
        q += __shfl_xor(q, 2);
        q += __shfl_xor(q, 4);
        q += __shfl_xor(q, 8);
        if ((lane & 15) == 0 && row < N)
            inv0[row] = 1.f / fmaxf(sqrtf(q), 1e-12f);
    }
}

// ---------------------------------------------------------------------------
// CSR build, pass 1: per-block LDS histogram of buckets (bucket = dst>>8).
// ---------------------------------------------------------------------------
__global__ __launch_bounds__(256) void hist1_kernel(
    const int* __restrict__ dst, int E, int EV, int nbuck,
    int* __restrict__ bucketCount)
{
    __shared__ int h[NBUCK_MAX];
    int tid = threadIdx.x;
    for (int j = tid; j < nbuck; j += 256) h[j] = 0;
    __syncthreads();
    int base = blockIdx.x * EPB;
    for (int k = 0; k < EPB / 256; ++k) {
        int i = base + k * 256 + tid;
        if (i < EV) {
            int d = (i < E) ? dst[i] : (i - E);
            atomicAdd(&h[d >> 8], 1);
        }
    }
    __syncthreads();
    for (int j = tid; j < nbuck; j += 256)
        if (h[j]) atomicAdd(&bucketCount[j], h[j]);
}

// ---------------------------------------------------------------------------
// CSR build, pass 2: single-WG exclusive scan of bucket counts.
// ---------------------------------------------------------------------------
__global__ __launch_bounds__(512) void bucket_scan_kernel(
    const int* __restrict__ bucketCount, int nbuck,
    int* __restrict__ bucketStart, int* __restrict__ gCursor)
{
    __shared__ int s[512];
    int t = threadIdx.x;
    int v = (t < nbuck) ? bucketCount[t] : 0;
    s[t] = v;
    __syncthreads();
    for (int off = 1; off < 512; off <<= 1) {
        int add = (t >= off) ? s[t - off] : 0;
        __syncthreads();
        s[t] += add;
        __syncthreads();
    }
    int incl = s[t];
    if (t < nbuck) {
        bucketStart[t] = incl - v;
        gCursor[t]     = incl - v;
        if (t == nbuck - 1) bucketStart[nbuck] = incl;
    }
}

// ---------------------------------------------------------------------------
// CSR build, pass 3: partition edges into bucket regions of `staged`.
// staged entry packs src (17b) | dstLocal (8b) << 17.
// ---------------------------------------------------------------------------
__global__ __launch_bounds__(256) void partition_kernel(
    const int* __restrict__ src, const int* __restrict__ dst,
    int E, int EV, int nbuck, int* __restrict__ gCursor,
    unsigned* __restrict__ staged)
{
    __shared__ int h[NBUCK_MAX];
    __shared__ int gb[NBUCK_MAX];
    int tid = threadIdx.x;
    for (int j = tid; j < nbuck; j += 256) h[j] = 0;
    __syncthreads();

    unsigned pk[EPB / 256];
    int      bk[EPB / 256];
    int base = blockIdx.x * EPB;
#pragma unroll
    for (int k = 0; k < EPB / 256; ++k) {
        int i = base + k * 256 + tid;
        if (i < EV) {
            int s, d;
            if (i < E) { s = src[i]; d = dst[i]; }
            else       { s = i - E;  d = s; }
            bk[k] = d >> 8;
            pk[k] = (unsigned)s | ((unsigned)(d & 255) << 17);
            atomicAdd(&h[bk[k]], 1);
        } else {
            bk[k] = -1;
        }
    }
    __syncthreads();
    for (int j = tid; j < nbuck; j += 256) {
        int c = h[j];
        if (c) gb[j] = atomicAdd(&gCursor[j], c);
        h[j] = 0;  // reuse as local cursor
    }
    __syncthreads();
#pragma unroll
    for (int k = 0; k < EPB / 256; ++k) {
        if (bk[k] >= 0) {
            int ofs = atomicAdd(&h[bk[k]], 1);
            staged[gb[bk[k]] + ofs] = pk[k];
        }
    }
}

// ---------------------------------------------------------------------------
// CSR build, pass 4: one WG per bucket -> counts/rowstart/esrc.
// ---------------------------------------------------------------------------
__global__ __launch_bounds__(256) void build_csr_kernel(
    const unsigned* __restrict__ staged, const int* __restrict__ bucketStart,
    int* __restrict__ counts, int* __restrict__ rowstart,
    int* __restrict__ esrc, int N)
{
    __shared__ int hist[256];
    __shared__ int s[256];
    __shared__ int cur[256];
    int b   = blockIdx.x;
    int tid = threadIdx.x;
    int start = bucketStart[b];
    int end   = bucketStart[b + 1];

    hist[tid] = 0;
    __syncthreads();
    for (int i = start + tid; i < end; i += 256)
        atomicAdd(&hist[(staged[i] >> 17) & 255], 1);
    __syncthreads();

    int v = hist[tid];
    s[tid] = v;
    __syncthreads();
    for (int off = 1; off < 256; off <<= 1) {
        int add = (tid >= off) ? s[tid - off] : 0;
        __syncthreads();
        s[tid] += add;
        __syncthreads();
    }
    int excl = s[tid] - v;
    int dstg = b * 256 + tid;
    if (dstg < N) {
        counts[dstg]   = v;
        rowstart[dstg] = start + excl;
    }
    cur[tid] = start + excl;
    __syncthreads();

    for (int i = start + tid; i < end; i += 256) {
        unsigned pk = staged[i];
        int dl  = (pk >> 17) & 255;
        int pos = atomicAdd(&cur[dl], 1);
        esrc[pos] = (int)(pk & 0x1FFFFu);
    }
}

// ---------------------------------------------------------------------------
// Attention layer: ONE WAVE PER NODE, 4 edges per iteration.
// lane = (edge-slot e = lane>>4, feature j = lane&15).
// Dot via 4 intra-16 shuffles; group partials combined at end.
// Softmax shift-invariance: constant shift |beta| since cos in [-1,1].
// ---------------------------------------------------------------------------
__global__ __launch_bounds__(256) void agg_kernel(
    const float* __restrict__ h, const float* __restrict__ inv,
    const int* __restrict__ esrc, const int* __restrict__ rowstart,
    const int* __restrict__ counts, const float* __restrict__ beta_p,
    float* __restrict__ hout, float* __restrict__ invout, int N)
{
    int node = (blockIdx.x * blockDim.x + threadIdx.x) >> 6;
    if (node >= N) return;
    int lane = threadIdx.x & 63;
    int j = lane & 15;

    float beta  = *beta_p;
    float shift = fabsf(beta);
    float hd   = h[(size_t)node * HID + j];
    float invd = inv[node];
    int start = rowstart[node];
    int cnt   = counts[node];

    float denom = 0.f, acc = 0.f;
    for (int t = (lane >> 4); t < cnt; t += 4) {
        int s    = esrc[start + t];
        float hs = h[(size_t)s * HID + j];
        float p  = hs * hd;
        p += __shfl_xor(p, 1);
        p += __shfl_xor(p, 2);
        p += __shfl_xor(p, 4);
        p += __shfl_xor(p, 8);
        float w = __expf(beta * (p * invd * inv[s]) - shift);
        denom += w;
        acc   += w * hs;
    }
    // combine the 4 edge-groups
    denom += __shfl_xor(denom, 16);
    denom += __shfl_xor(denom, 32);
    acc   += __shfl_xor(acc, 16);
    acc   += __shfl_xor(acc, 32);

    float o = acc / denom;
    if (lane < 16) hout[(size_t)node * HID + j] = o;

    float q = o * o;
    q += __shfl_xor(q, 1);
    q += __shfl_xor(q, 2);
    q += __shfl_xor(q, 4);
    q += __shfl_xor(q, 8);
    if (lane == 0) invout[node] = 1.f / fmaxf(sqrtf(q), 1e-12f);
}

// ---------------------------------------------------------------------------
// K5: out = log_softmax(h2 @ W2 + b2). One wave per row, lane = class.
// ---------------------------------------------------------------------------
__global__ __launch_bounds__(256) void out_kernel(
    const float* __restrict__ h2, const float* __restrict__ W2,
    const float* __restrict__ b2, float* __restrict__ out, int N)
{
    int wave = (blockIdx.x * blockDim.x + threadIdx.x) >> 6;
    int lane = threadIdx.x & 63;
    if (wave >= N) return;

    float hv = (lane < HID) ? h2[(size_t)wave * HID + lane] : 0.f;
    float acc = b2[lane];
#pragma unroll
    for (int k = 0; k < HID; ++k) {
        float hk = __shfl(hv, k);
        acc += hk * W2[k * NCLS + lane];
    }
    float m = acc;
    for (int off = 32; off > 0; off >>= 1) m = fmaxf(m, __shfl_xor(m, off));
    float e = __expf(acc - m);
    float ssum = e;
    for (int off = 32; off > 0; off >>= 1) ssum += __shfl_xor(ssum, off);
    out[(size_t)wave * NCLS + lane] = (acc - m) - __logf(ssum);
}

// ---------------------------------------------------------------------------
extern "C" void kernel_launch(void* const* d_in, const int* in_sizes, int n_in,
                              void* d_out, int out_size, void* d_ws, size_t ws_size,
                              hipStream_t stream)
{
    const float* x     = (const float*)d_in[0];
    const int*   eidx  = (const int*)d_in[1];
    const float* W1    = (const float*)d_in[2];
    const float* b1    = (const float*)d_in[3];
    const float* W2    = (const float*)d_in[4];
    const float* b2    = (const float*)d_in[5];
    const float* beta1 = (const float*)d_in[6];
    const float* beta2 = (const float*)d_in[7];

    int N = in_sizes[0] / F_IN;       // 100000
    int E = in_sizes[1] / 2;          // 3200000
    const int* src = eidx;
    const int* dst = eidx + E;
    float* out = (float*)d_out;

    int EV    = E + N;                // virtual edges (incl. self-loops)
    int nbuck = (N + 255) / 256;      // 391

    char* wptr = (char*)d_ws;
    auto alloc = [&](size_t bytes) -> char* {
        char* p = wptr;
        wptr += (bytes + 255) / 256 * 256;
        return p;
    };
    float*    h0       = (float*)alloc((size_t)N * HID * 4);
    float*    inv0     = (float*)alloc((size_t)N * 4);
    float*    h1       = (float*)alloc((size_t)N * HID * 4);
    float*    inv1     = (float*)alloc((size_t)N * 4);
    float*    h2       = (float*)alloc((size_t)N * HID * 4);
    float*    inv2     = (float*)alloc((size_t)N * 4);
    int*      counts   = (int*)alloc((size_t)N * 4);
    int*      rowstart = (int*)alloc((size_t)(N + 1) * 4);
    int*      esrc     = (int*)alloc((size_t)EV * 4);
    unsigned* staged   = (unsigned*)alloc((size_t)EV * 4);
    int*      bucketCount = (int*)alloc((size_t)(nbuck + 1) * 4);
    int*      bucketStart = (int*)alloc((size_t)(nbuck + 1) * 4);
    int*      gCursor     = (int*)alloc((size_t)nbuck * 4);

    int ebBlocks = (EV + EPB - 1) / EPB;  // 403

    // CSR build (counting sort, write-locality aware)
    hipMemsetAsync(bucketCount, 0, (size_t)nbuck * 4, stream);
    hist1_kernel<<<ebBlocks, 256, 0, stream>>>(dst, E, EV, nbuck, bucketCount);
    bucket_scan_kernel<<<1, 512, 0, stream>>>(bucketCount, nbuck, bucketStart, gCursor);
    partition_kernel<<<ebBlocks, 256, 0, stream>>>(src, dst, E, EV, nbuck, gCursor, staged);
    build_csr_kernel<<<nbuck, 256, 0, stream>>>(staged, bucketStart, counts, rowstart,
                                                esrc, N);

    // h0 = relu(x@W1+b1), inv0
    int g1blocks = 1024;
    gemm1_kernel<<<g1blocks, 256, 0, stream>>>(x, W1, b1, h0, inv0, N, g1blocks * 4);

    // two attention layers: one wave per node
    int aggBlocks = (N + 3) / 4;   // 4 waves (nodes) per 256-thread block
    agg_kernel<<<aggBlocks, 256, 0, stream>>>(h0, inv0, esrc, rowstart, counts, beta1,
                                              h1, inv1, N);
    agg_kernel<<<aggBlocks, 256, 0, stream>>>(h1, inv1, esrc, rowstart, counts, beta2,
                                              h2, inv2, N);

    // out = log_softmax(h2@W2+b2)
    out_kernel<<<(N * 64 + 255) / 256, 256, 0, stream>>>(h2, W2, b2, out, N);
}

// Round 4
// 666.276 us; speedup vs baseline: 1.8202x; 1.8202x over previous
//
#include <hip/hip_runtime.h>
#include <hip/hip_bf16.h>

#define F_IN 512
#define HID 16
#define NCLS 64
#define NBUCK_MAX 512     // LDS sizing; actual nbuck = ceil(N/256) = 391
#define EPB 8192          // edges per block in hist/partition

// ---------------------------------------------------------------------------
// K1: h0 = relu(x @ W1 + b1), inv0 = 1/max(||h0||,eps)
// ONE ROW PER WAVE, low register pressure (no spills). Lane owns
// k in [8*lane, 8*lane+8). W1 rows re-read per row (L1-resident, 32 KB).
// Value-halving shuffle tree: 17 shuffles/row, output j lands on lane&15==j.
// ---------------------------------------------------------------------------
__global__ __launch_bounds__(256) void gemm1_kernel(
    const float* __restrict__ x, const float* __restrict__ W1,
    const float* __restrict__ b1, float* __restrict__ h0,
    float* __restrict__ inv0, int N, int totalWaves)
{
    int wid  = (blockIdx.x * blockDim.x + threadIdx.x) >> 6;
    int lane = threadIdx.x & 63;
    float bias = b1[lane & 15];
    bool s3 = (lane & 8) != 0;
    bool s2 = (lane & 4) != 0;
    bool s1 = (lane & 2) != 0;
    bool s0 = (lane & 1) != 0;

    for (int row = wid; row < N; row += totalWaves) {
        // x slice: 8 contiguous floats at k = 8*lane
        const float4* xp = (const float4*)(x + (size_t)row * F_IN + 8 * lane);
        float4 ta = xp[0], tb = xp[1];
        float xv[8] = {ta.x, ta.y, ta.z, ta.w, tb.x, tb.y, tb.z, tb.w};

        float acc[16];
#pragma unroll
        for (int i = 0; i < 16; ++i) acc[i] = 0.f;

#pragma unroll
        for (int kk = 0; kk < 8; ++kk) {
            const float4* wp = (const float4*)(W1 + (size_t)(8 * lane + kk) * HID);
            float xs = xv[kk];
#pragma unroll
            for (int jj = 0; jj < 4; ++jj) {
                float4 t = wp[jj];
                acc[jj * 4 + 0] += xs * t.x;
                acc[jj * 4 + 1] += xs * t.y;
                acc[jj * 4 + 2] += xs * t.z;
                acc[jj * 4 + 3] += xs * t.w;
            }
        }

        // Value-halving reduce within each 16-lane group.
        // After step xor m: lane holds outputs with bit pattern accumulating
        // lane's own low bits; ends with output j on lane (lane&15)==j.
#pragma unroll
        for (int i = 0; i < 8; ++i) {
            float k = s3 ? acc[i + 8] : acc[i];
            float s = s3 ? acc[i] : acc[i + 8];
            acc[i] = k + __shfl_xor(s, 8);
        }
#pragma unroll
        for (int i = 0; i < 4; ++i) {
            float k = s2 ? acc[i + 4] : acc[i];
            float s = s2 ? acc[i] : acc[i + 4];
            acc[i] = k + __shfl_xor(s, 4);
        }
#pragma unroll
        for (int i = 0; i < 2; ++i) {
            float k = s1 ? acc[i + 2] : acc[i];
            float s = s1 ? acc[i] : acc[i + 2];
            acc[i] = k + __shfl_xor(s, 2);
        }
        {
            float k = s0 ? acc[1] : acc[0];
            float s = s0 ? acc[0] : acc[1];
            acc[0] = k + __shfl_xor(s, 1);
        }
        // merge the four 16-lane k-groups
        acc[0] += __shfl_xor(acc[0], 16);
        acc[0] += __shfl_xor(acc[0], 32);

        float val = fmaxf(acc[0] + bias, 0.f);
        if (lane < 16) h0[(size_t)row * HID + lane] = val;

        float q = val * val;
        q += __shfl_xor(q, 1);
        q += __shfl_xor(q, 2);
        q += __shfl_xor(q, 4);
        q += __shfl_xor(q, 8);
        if (lane == 0) inv0[row] = 1.f / fmaxf(sqrtf(q), 1e-12f);
    }
}

// ---------------------------------------------------------------------------
// CSR build, pass 1: per-block LDS histogram of buckets (bucket = dst>>8).
// ---------------------------------------------------------------------------
__global__ __launch_bounds__(256) void hist1_kernel(
    const int* __restrict__ dst, int E, int EV, int nbuck,
    int* __restrict__ bucketCount)
{
    __shared__ int h[NBUCK_MAX];
    int tid = threadIdx.x;
    for (int j = tid; j < nbuck; j += 256) h[j] = 0;
    __syncthreads();
    int base = blockIdx.x * EPB;
    for (int k = 0; k < EPB / 256; ++k) {
        int i = base + k * 256 + tid;
        if (i < EV) {
            int d = (i < E) ? dst[i] : (i - E);
            atomicAdd(&h[d >> 8], 1);
        }
    }
    __syncthreads();
    for (int j = tid; j < nbuck; j += 256)
        if (h[j]) atomicAdd(&bucketCount[j], h[j]);
}

// ---------------------------------------------------------------------------
// CSR build, pass 2: single-WG exclusive scan of bucket counts.
// ---------------------------------------------------------------------------
__global__ __launch_bounds__(512) void bucket_scan_kernel(
    const int* __restrict__ bucketCount, int nbuck,
    int* __restrict__ bucketStart, int* __restrict__ gCursor)
{
    __shared__ int s[512];
    int t = threadIdx.x;
    int v = (t < nbuck) ? bucketCount[t] : 0;
    s[t] = v;
    __syncthreads();
    for (int off = 1; off < 512; off <<= 1) {
        int add = (t >= off) ? s[t - off] : 0;
        __syncthreads();
        s[t] += add;
        __syncthreads();
    }
    int incl = s[t];
    if (t < nbuck) {
        bucketStart[t] = incl - v;
        gCursor[t]     = incl - v;
        if (t == nbuck - 1) bucketStart[nbuck] = incl;
    }
}

// ---------------------------------------------------------------------------
// CSR build, pass 3: partition edges into bucket regions of `staged`.
// staged entry packs src (17b) | dstLocal (8b) << 17.
// ---------------------------------------------------------------------------
__global__ __launch_bounds__(256) void partition_kernel(
    const int* __restrict__ src, const int* __restrict__ dst,
    int E, int EV, int nbuck, int* __restrict__ gCursor,
    unsigned* __restrict__ staged)
{
    __shared__ int h[NBUCK_MAX];
    __shared__ int gb[NBUCK_MAX];
    int tid = threadIdx.x;
    for (int j = tid; j < nbuck; j += 256) h[j] = 0;
    __syncthreads();

    unsigned pk[EPB / 256];
    int      bk[EPB / 256];
    int base = blockIdx.x * EPB;
#pragma unroll
    for (int k = 0; k < EPB / 256; ++k) {
        int i = base + k * 256 + tid;
        if (i < EV) {
            int s, d;
            if (i < E) { s = src[i]; d = dst[i]; }
            else       { s = i - E;  d = s; }
            bk[k] = d >> 8;
            pk[k] = (unsigned)s | ((unsigned)(d & 255) << 17);
            atomicAdd(&h[bk[k]], 1);
        } else {
            bk[k] = -1;
        }
    }
    __syncthreads();
    for (int j = tid; j < nbuck; j += 256) {
        int c = h[j];
        if (c) gb[j] = atomicAdd(&gCursor[j], c);
        h[j] = 0;  // reuse as local cursor
    }
    __syncthreads();
#pragma unroll
    for (int k = 0; k < EPB / 256; ++k) {
        if (bk[k] >= 0) {
            int ofs = atomicAdd(&h[bk[k]], 1);
            staged[gb[bk[k]] + ofs] = pk[k];
        }
    }
}

// ---------------------------------------------------------------------------
// CSR build, pass 4: one WG per bucket -> counts/rowstart/esrc.
// ---------------------------------------------------------------------------
__global__ __launch_bounds__(256) void build_csr_kernel(
    const unsigned* __restrict__ staged, const int* __restrict__ bucketStart,
    int* __restrict__ counts, int* __restrict__ rowstart,
    int* __restrict__ esrc, int N)
{
    __shared__ int hist[256];
    __shared__ int s[256];
    __shared__ int cur[256];
    int b   = blockIdx.x;
    int tid = threadIdx.x;
    int start = bucketStart[b];
    int end   = bucketStart[b + 1];

    hist[tid] = 0;
    __syncthreads();
    for (int i = start + tid; i < end; i += 256)
        atomicAdd(&hist[(staged[i] >> 17) & 255], 1);
    __syncthreads();

    int v = hist[tid];
    s[tid] = v;
    __syncthreads();
    for (int off = 1; off < 256; off <<= 1) {
        int add = (tid >= off) ? s[tid - off] : 0;
        __syncthreads();
        s[tid] += add;
        __syncthreads();
    }
    int excl = s[tid] - v;
    int dstg = b * 256 + tid;
    if (dstg < N) {
        counts[dstg]   = v;
        rowstart[dstg] = start + excl;
    }
    cur[tid] = start + excl;
    __syncthreads();

    for (int i = start + tid; i < end; i += 256) {
        unsigned pk = staged[i];
        int dl  = (pk >> 17) & 255;
        int pos = atomicAdd(&cur[dl], 1);
        esrc[pos] = (int)(pk & 0x1FFFFu);
    }
}

// ---------------------------------------------------------------------------
// Attention layer: ONE WAVE PER NODE, 4 edges per iteration.
// lane = (edge-slot e = lane>>4, feature j = lane&15).
// Softmax shift-invariance: constant shift |beta| since cos in [-1,1].
// ---------------------------------------------------------------------------
__global__ __launch_bounds__(256) void agg_kernel(
    const float* __restrict__ h, const float* __restrict__ inv,
    const int* __restrict__ esrc, const int* __restrict__ rowstart,
    const int* __restrict__ counts, const float* __restrict__ beta_p,
    float* __restrict__ hout, float* __restrict__ invout, int N)
{
    int node = (blockIdx.x * blockDim.x + threadIdx.x) >> 6;
    if (node >= N) return;
    int lane = threadIdx.x & 63;
    int j = lane & 15;

    float beta  = *beta_p;
    float shift = fabsf(beta);
    float hd   = h[(size_t)node * HID + j];
    float invd = inv[node];
    int start = rowstart[node];
    int cnt   = counts[node];

    float denom = 0.f, acc = 0.f;
    for (int t = (lane >> 4); t < cnt; t += 4) {
        int s    = esrc[start + t];
        float hs = h[(size_t)s * HID + j];
        float p  = hs * hd;
        p += __shfl_xor(p, 1);
        p += __shfl_xor(p, 2);
        p += __shfl_xor(p, 4);
        p += __shfl_xor(p, 8);
        float w = __expf(beta * (p * invd * inv[s]) - shift);
        denom += w;
        acc   += w * hs;
    }
    denom += __shfl_xor(denom, 16);
    denom += __shfl_xor(denom, 32);
    acc   += __shfl_xor(acc, 16);
    acc   += __shfl_xor(acc, 32);

    float o = acc / denom;
    if (lane < 16) hout[(size_t)node * HID + j] = o;

    float q = o * o;
    q += __shfl_xor(q, 1);
    q += __shfl_xor(q, 2);
    q += __shfl_xor(q, 4);
    q += __shfl_xor(q, 8);
    if (lane == 0) invout[node] = 1.f / fmaxf(sqrtf(q), 1e-12f);
}

// ---------------------------------------------------------------------------
// K5: out = log_softmax(h2 @ W2 + b2). One wave per row, lane = class.
// ---------------------------------------------------------------------------
__global__ __launch_bounds__(256) void out_kernel(
    const float* __restrict__ h2, const float* __restrict__ W2,
    const float* __restrict__ b2, float* __restrict__ out, int N)
{
    int wave = (blockIdx.x * blockDim.x + threadIdx.x) >> 6;
    int lane = threadIdx.x & 63;
    if (wave >= N) return;

    float hv = (lane < HID) ? h2[(size_t)wave * HID + lane] : 0.f;
    float acc = b2[lane];
#pragma unroll
    for (int k = 0; k < HID; ++k) {
        float hk = __shfl(hv, k);
        acc += hk * W2[k * NCLS + lane];
    }
    float m = acc;
    for (int off = 32; off > 0; off >>= 1) m = fmaxf(m, __shfl_xor(m, off));
    float e = __expf(acc - m);
    float ssum = e;
    for (int off = 32; off > 0; off >>= 1) ssum += __shfl_xor(ssum, off);
    out[(size_t)wave * NCLS + lane] = (acc - m) - __logf(ssum);
}

// ---------------------------------------------------------------------------
extern "C" void kernel_launch(void* const* d_in, const int* in_sizes, int n_in,
                              void* d_out, int out_size, void* d_ws, size_t ws_size,
                              hipStream_t stream)
{
    const float* x     = (const float*)d_in[0];
    const int*   eidx  = (const int*)d_in[1];
    const float* W1    = (const float*)d_in[2];
    const float* b1    = (const float*)d_in[3];
    const float* W2    = (const float*)d_in[4];
    const float* b2    = (const float*)d_in[5];
    const float* beta1 = (const float*)d_in[6];
    const float* beta2 = (const float*)d_in[7];

    int N = in_sizes[0] / F_IN;       // 100000
    int E = in_sizes[1] / 2;          // 3200000
    const int* src = eidx;
    const int* dst = eidx + E;
    float* out = (float*)d_out;

    int EV    = E + N;                // virtual edges (incl. self-loops)
    int nbuck = (N + 255) / 256;      // 391

    char* wptr = (char*)d_ws;
    auto alloc = [&](size_t bytes) -> char* {
        char* p = wptr;
        wptr += (bytes + 255) / 256 * 256;
        return p;
    };
    float*    h0       = (float*)alloc((size_t)N * HID * 4);
    float*    inv0     = (float*)alloc((size_t)N * 4);
    float*    h1       = (float*)alloc((size_t)N * HID * 4);
    float*    inv1     = (float*)alloc((size_t)N * 4);
    float*    h2       = (float*)alloc((size_t)N * HID * 4);
    float*    inv2     = (float*)alloc((size_t)N * 4);
    int*      counts   = (int*)alloc((size_t)N * 4);
    int*      rowstart = (int*)alloc((size_t)(N + 1) * 4);
    int*      esrc     = (int*)alloc((size_t)EV * 4);
    unsigned* staged   = (unsigned*)alloc((size_t)EV * 4);
    int*      bucketCount = (int*)alloc((size_t)(nbuck + 1) * 4);
    int*      bucketStart = (int*)alloc((size_t)(nbuck + 1) * 4);
    int*      gCursor     = (int*)alloc((size_t)nbuck * 4);

    int ebBlocks = (EV + EPB - 1) / EPB;  // 403

    // CSR build (counting sort, write-locality aware)
    hipMemsetAsync(bucketCount, 0, (size_t)nbuck * 4, stream);
    hist1_kernel<<<ebBlocks, 256, 0, stream>>>(dst, E, EV, nbuck, bucketCount);
    bucket_scan_kernel<<<1, 512, 0, stream>>>(bucketCount, nbuck, bucketStart, gCursor);
    partition_kernel<<<ebBlocks, 256, 0, stream>>>(src, dst, E, EV, nbuck, gCursor, staged);
    build_csr_kernel<<<nbuck, 256, 0, stream>>>(staged, bucketStart, counts, rowstart,
                                                esrc, N);

    // h0 = relu(x@W1+b1), inv0
    int g1blocks = 2048;   // 8192 waves = 8/SIMD: enough to stream 205 MB of x
    gemm1_kernel<<<g1blocks, 256, 0, stream>>>(x, W1, b1, h0, inv0, N, g1blocks * 4);

    // two attention layers: one wave per node
    int aggBlocks = (N + 3) / 4;   // 4 waves (nodes) per 256-thread block
    agg_kernel<<<aggBlocks, 256, 0, stream>>>(h0, inv0, esrc, rowstart, counts, beta1,
                                              h1, inv1, N);
    agg_kernel<<<aggBlocks, 256, 0, stream>>>(h1, inv1, esrc, rowstart, counts, beta2,
                                              h2, inv2, N);

    // out = log_softmax(h2@W2+b2)
    out_kernel<<<(N * 64 + 255) / 256, 256, 0, stream>>>(h2, W2, b2, out, N);
}

// Round 5
// 584.944 us; speedup vs baseline: 2.0733x; 1.1390x over previous
//
#include <hip/hip_runtime.h>
#include <hip/hip_bf16.h>

#define F_IN 512
#define HID 16
#define NCLS 64
#define NBUCK_MAX 512     // LDS sizing; actual nbuck = ceil(N/256) = 391
#define EPB 8192          // edges per block in hist/partition

// ---------------------------------------------------------------------------
// K1: h0 = relu(x @ W1 + b1), inv0 = 1/max(||h0||,eps)
// ONE ROW PER WAVE, low register pressure (no spills). Lane owns
// k in [8*lane, 8*lane+8). W1 rows re-read per row (L1-resident, 32 KB).
// Value-halving shuffle tree: 17 shuffles/row, output j lands on lane&15==j.
// ---------------------------------------------------------------------------
__global__ __launch_bounds__(256) void gemm1_kernel(
    const float* __restrict__ x, const float* __restrict__ W1,
    const float* __restrict__ b1, float* __restrict__ h0,
    float* __restrict__ inv0, int N, int totalWaves)
{
    int wid  = (blockIdx.x * blockDim.x + threadIdx.x) >> 6;
    int lane = threadIdx.x & 63;
    float bias = b1[lane & 15];
    bool s3 = (lane & 8) != 0;
    bool s2 = (lane & 4) != 0;
    bool s1 = (lane & 2) != 0;
    bool s0 = (lane & 1) != 0;

    for (int row = wid; row < N; row += totalWaves) {
        const float4* xp = (const float4*)(x + (size_t)row * F_IN + 8 * lane);
        float4 ta = xp[0], tb = xp[1];
        float xv[8] = {ta.x, ta.y, ta.z, ta.w, tb.x, tb.y, tb.z, tb.w};

        float acc[16];
#pragma unroll
        for (int i = 0; i < 16; ++i) acc[i] = 0.f;

#pragma unroll
        for (int kk = 0; kk < 8; ++kk) {
            const float4* wp = (const float4*)(W1 + (size_t)(8 * lane + kk) * HID);
            float xs = xv[kk];
#pragma unroll
            for (int jj = 0; jj < 4; ++jj) {
                float4 t = wp[jj];
                acc[jj * 4 + 0] += xs * t.x;
                acc[jj * 4 + 1] += xs * t.y;
                acc[jj * 4 + 2] += xs * t.z;
                acc[jj * 4 + 3] += xs * t.w;
            }
        }

#pragma unroll
        for (int i = 0; i < 8; ++i) {
            float k = s3 ? acc[i + 8] : acc[i];
            float s = s3 ? acc[i] : acc[i + 8];
            acc[i] = k + __shfl_xor(s, 8);
        }
#pragma unroll
        for (int i = 0; i < 4; ++i) {
            float k = s2 ? acc[i + 4] : acc[i];
            float s = s2 ? acc[i] : acc[i + 4];
            acc[i] = k + __shfl_xor(s, 4);
        }
#pragma unroll
        for (int i = 0; i < 2; ++i) {
            float k = s1 ? acc[i + 2] : acc[i];
            float s = s1 ? acc[i] : acc[i + 2];
            acc[i] = k + __shfl_xor(s, 2);
        }
        {
            float k = s0 ? acc[1] : acc[0];
            float s = s0 ? acc[0] : acc[1];
            acc[0] = k + __shfl_xor(s, 1);
        }
        acc[0] += __shfl_xor(acc[0], 16);
        acc[0] += __shfl_xor(acc[0], 32);

        float val = fmaxf(acc[0] + bias, 0.f);
        if (lane < 16) h0[(size_t)row * HID + lane] = val;

        float q = val * val;
        q += __shfl_xor(q, 1);
        q += __shfl_xor(q, 2);
        q += __shfl_xor(q, 4);
        q += __shfl_xor(q, 8);
        if (lane == 0) inv0[row] = 1.f / fmaxf(sqrtf(q), 1e-12f);
    }
}

// ---------------------------------------------------------------------------
// CSR build, pass 1: per-block LDS histogram of buckets (bucket = dst>>8).
// ---------------------------------------------------------------------------
__global__ __launch_bounds__(256) void hist1_kernel(
    const int* __restrict__ dst, int E, int EV, int nbuck,
    int* __restrict__ bucketCount)
{
    __shared__ int h[NBUCK_MAX];
    int tid = threadIdx.x;
    for (int j = tid; j < nbuck; j += 256) h[j] = 0;
    __syncthreads();
    int base = blockIdx.x * EPB;
    for (int k = 0; k < EPB / 256; ++k) {
        int i = base + k * 256 + tid;
        if (i < EV) {
            int d = (i < E) ? dst[i] : (i - E);
            atomicAdd(&h[d >> 8], 1);
        }
    }
    __syncthreads();
    for (int j = tid; j < nbuck; j += 256)
        if (h[j]) atomicAdd(&bucketCount[j], h[j]);
}

// ---------------------------------------------------------------------------
// CSR build, pass 2: single-WG exclusive scan of bucket counts.
// ---------------------------------------------------------------------------
__global__ __launch_bounds__(512) void bucket_scan_kernel(
    const int* __restrict__ bucketCount, int nbuck,
    int* __restrict__ bucketStart, int* __restrict__ gCursor)
{
    __shared__ int s[512];
    int t = threadIdx.x;
    int v = (t < nbuck) ? bucketCount[t] : 0;
    s[t] = v;
    __syncthreads();
    for (int off = 1; off < 512; off <<= 1) {
        int add = (t >= off) ? s[t - off] : 0;
        __syncthreads();
        s[t] += add;
        __syncthreads();
    }
    int incl = s[t];
    if (t < nbuck) {
        bucketStart[t] = incl - v;
        gCursor[t]     = incl - v;
        if (t == nbuck - 1) bucketStart[nbuck] = incl;
    }
}

// ---------------------------------------------------------------------------
// CSR build, pass 3: partition edges into bucket regions of `staged`.
// Two passes over the block's edge range (second re-read is L1/L2-hot)
// instead of 64-VGPR register caching. One global atomic per (block,bucket).
// staged entry packs src (17b) | dstLocal (8b) << 17.
// ---------------------------------------------------------------------------
__global__ __launch_bounds__(256) void partition_kernel(
    const int* __restrict__ src, const int* __restrict__ dst,
    int E, int EV, int nbuck, int* __restrict__ gCursor,
    unsigned* __restrict__ staged)
{
    __shared__ int h[NBUCK_MAX];
    __shared__ int gb[NBUCK_MAX];
    int tid = threadIdx.x;
    for (int j = tid; j < nbuck; j += 256) h[j] = 0;
    __syncthreads();

    int base = blockIdx.x * EPB;
    // pass A: local histogram
    for (int k = 0; k < EPB / 256; ++k) {
        int i = base + k * 256 + tid;
        if (i < EV) {
            int d = (i < E) ? dst[i] : (i - E);
            atomicAdd(&h[d >> 8], 1);
        }
    }
    __syncthreads();
    // reserve contiguous chunks
    for (int j = tid; j < nbuck; j += 256) {
        int c = h[j];
        if (c) gb[j] = atomicAdd(&gCursor[j], c);
        h[j] = 0;  // reuse as local cursor
    }
    __syncthreads();
    // pass B: re-read edges, write packed entries into reserved chunks
    for (int k = 0; k < EPB / 256; ++k) {
        int i = base + k * 256 + tid;
        if (i < EV) {
            int s, d;
            if (i < E) { s = src[i]; d = dst[i]; }
            else       { s = i - E;  d = s; }
            int bkt = d >> 8;
            int ofs = atomicAdd(&h[bkt], 1);
            staged[gb[bkt] + ofs] = (unsigned)s | ((unsigned)(d & 255) << 17);
        }
    }
}

// ---------------------------------------------------------------------------
// CSR build, pass 4: one WG per bucket -> counts/rowstart/esrc.
// ---------------------------------------------------------------------------
__global__ __launch_bounds__(256) void build_csr_kernel(
    const unsigned* __restrict__ staged, const int* __restrict__ bucketStart,
    int* __restrict__ counts, int* __restrict__ rowstart,
    int* __restrict__ esrc, int N)
{
    __shared__ int hist[256];
    __shared__ int s[256];
    __shared__ int cur[256];
    int b   = blockIdx.x;
    int tid = threadIdx.x;
    int start = bucketStart[b];
    int end   = bucketStart[b + 1];

    hist[tid] = 0;
    __syncthreads();
    for (int i = start + tid; i < end; i += 256)
        atomicAdd(&hist[(staged[i] >> 17) & 255], 1);
    __syncthreads();

    int v = hist[tid];
    s[tid] = v;
    __syncthreads();
    for (int off = 1; off < 256; off <<= 1) {
        int add = (tid >= off) ? s[tid - off] : 0;
        __syncthreads();
        s[tid] += add;
        __syncthreads();
    }
    int excl = s[tid] - v;
    int dstg = b * 256 + tid;
    if (dstg < N) {
        counts[dstg]   = v;
        rowstart[dstg] = start + excl;
    }
    cur[tid] = start + excl;
    __syncthreads();

    for (int i = start + tid; i < end; i += 256) {
        unsigned pk = staged[i];
        int dl  = (pk >> 17) & 255;
        int pos = atomicAdd(&cur[dl], 1);
        esrc[pos] = (int)(pk & 0x1FFFFu);
    }
}

// ---------------------------------------------------------------------------
// Attention layer: ONE WAVE PER NODE, 16 edges in flight, 4 lanes per edge.
// lane = (edge-slot e = lane>>2, feature-quad q = lane&3); each lane holds
// float4 of features. Dot: 4 FMAs + 2 shuffles. 16 concurrent 64B gathers
// per wave (4x the MLP of the 4-edge layout).
// Softmax shift-invariance: constant shift |beta| since cos in [-1,1].
// ---------------------------------------------------------------------------
__global__ __launch_bounds__(256) void agg_kernel(
    const float* __restrict__ h, const float* __restrict__ inv,
    const int* __restrict__ esrc, const int* __restrict__ rowstart,
    const int* __restrict__ counts, const float* __restrict__ beta_p,
    float* __restrict__ hout, float* __restrict__ invout, int N)
{
    int node = (blockIdx.x * blockDim.x + threadIdx.x) >> 6;
    if (node >= N) return;
    int lane = threadIdx.x & 63;
    int q = lane & 3;        // feature quad: features 4q..4q+3
    int e = lane >> 2;       // edge slot 0..15

    float beta  = *beta_p;
    float shift = fabsf(beta);
    float4 hd4  = ((const float4*)(h + (size_t)node * HID))[q];
    float  invd = inv[node];
    int start = rowstart[node];
    int cnt   = counts[node];

    float denom = 0.f;
    float4 acc = make_float4(0.f, 0.f, 0.f, 0.f);
    for (int t = e; t < cnt; t += 16) {
        int s = esrc[start + t];
        float4 hs4 = ((const float4*)(h + (size_t)s * HID))[q];
        float invs = inv[s];
        float p = hs4.x * hd4.x + hs4.y * hd4.y + hs4.z * hd4.z + hs4.w * hd4.w;
        p += __shfl_xor(p, 1);
        p += __shfl_xor(p, 2);     // full dot in all 4 lanes of the quad
        float w = __expf(beta * (p * invd * invs) - shift);
        denom += w;
        acc.x += w * hs4.x;
        acc.y += w * hs4.y;
        acc.z += w * hs4.z;
        acc.w += w * hs4.w;
    }
    // reduce across the 16 edge slots (lane bits 2..5)
#pragma unroll
    for (int off = 4; off <= 32; off <<= 1) {
        denom += __shfl_xor(denom, off);
        acc.x += __shfl_xor(acc.x, off);
        acc.y += __shfl_xor(acc.y, off);
        acc.z += __shfl_xor(acc.z, off);
        acc.w += __shfl_xor(acc.w, off);
    }
    float rd = 1.f / denom;        // denom>0 guaranteed by self-loop
    float4 o = make_float4(acc.x * rd, acc.y * rd, acc.z * rd, acc.w * rd);
    if (lane < 4) ((float4*)(hout + (size_t)node * HID))[q] = o;

    float ss = o.x * o.x + o.y * o.y + o.z * o.z + o.w * o.w;
    ss += __shfl_xor(ss, 1);
    ss += __shfl_xor(ss, 2);
    if (lane == 0) invout[node] = 1.f / fmaxf(sqrtf(ss), 1e-12f);
}

// ---------------------------------------------------------------------------
// K5: out = log_softmax(h2 @ W2 + b2). One wave per row, lane = class.
// ---------------------------------------------------------------------------
__global__ __launch_bounds__(256) void out_kernel(
    const float* __restrict__ h2, const float* __restrict__ W2,
    const float* __restrict__ b2, float* __restrict__ out, int N)
{
    int wave = (blockIdx.x * blockDim.x + threadIdx.x) >> 6;
    int lane = threadIdx.x & 63;
    if (wave >= N) return;

    float hv = (lane < HID) ? h2[(size_t)wave * HID + lane] : 0.f;
    float acc = b2[lane];
#pragma unroll
    for (int k = 0; k < HID; ++k) {
        float hk = __shfl(hv, k);
        acc += hk * W2[k * NCLS + lane];
    }
    float m = acc;
    for (int off = 32; off > 0; off >>= 1) m = fmaxf(m, __shfl_xor(m, off));
    float e = __expf(acc - m);
    float ssum = e;
    for (int off = 32; off > 0; off >>= 1) ssum += __shfl_xor(ssum, off);
    out[(size_t)wave * NCLS + lane] = (acc - m) - __logf(ssum);
}

// ---------------------------------------------------------------------------
extern "C" void kernel_launch(void* const* d_in, const int* in_sizes, int n_in,
                              void* d_out, int out_size, void* d_ws, size_t ws_size,
                              hipStream_t stream)
{
    const float* x     = (const float*)d_in[0];
    const int*   eidx  = (const int*)d_in[1];
    const float* W1    = (const float*)d_in[2];
    const float* b1    = (const float*)d_in[3];
    const float* W2    = (const float*)d_in[4];
    const float* b2    = (const float*)d_in[5];
    const float* beta1 = (const float*)d_in[6];
    const float* beta2 = (const float*)d_in[7];

    int N = in_sizes[0] / F_IN;       // 100000
    int E = in_sizes[1] / 2;          // 3200000
    const int* src = eidx;
    const int* dst = eidx + E;
    float* out = (float*)d_out;

    int EV    = E + N;                // virtual edges (incl. self-loops)
    int nbuck = (N + 255) / 256;      // 391

    char* wptr = (char*)d_ws;
    auto alloc = [&](size_t bytes) -> char* {
        char* p = wptr;
        wptr += (bytes + 255) / 256 * 256;
        return p;
    };
    float*    h0       = (float*)alloc((size_t)N * HID * 4);
    float*    inv0     = (float*)alloc((size_t)N * 4);
    float*    h1       = (float*)alloc((size_t)N * HID * 4);
    float*    inv1     = (float*)alloc((size_t)N * 4);
    float*    h2       = (float*)alloc((size_t)N * HID * 4);
    float*    inv2     = (float*)alloc((size_t)N * 4);
    int*      counts   = (int*)alloc((size_t)N * 4);
    int*      rowstart = (int*)alloc((size_t)(N + 1) * 4);
    int*      esrc     = (int*)alloc((size_t)EV * 4);
    unsigned* staged   = (unsigned*)alloc((size_t)EV * 4);
    int*      bucketCount = (int*)alloc((size_t)(nbuck + 1) * 4);
    int*      bucketStart = (int*)alloc((size_t)(nbuck + 1) * 4);
    int*      gCursor     = (int*)alloc((size_t)nbuck * 4);

    int ebBlocks = (EV + EPB - 1) / EPB;  // 403

    // CSR build (counting sort, write-locality aware)
    hipMemsetAsync(bucketCount, 0, (size_t)nbuck * 4, stream);
    hist1_kernel<<<ebBlocks, 256, 0, stream>>>(dst, E, EV, nbuck, bucketCount);
    bucket_scan_kernel<<<1, 512, 0, stream>>>(bucketCount, nbuck, bucketStart, gCursor);
    partition_kernel<<<ebBlocks, 256, 0, stream>>>(src, dst, E, EV, nbuck, gCursor, staged);
    build_csr_kernel<<<nbuck, 256, 0, stream>>>(staged, bucketStart, counts, rowstart,
                                                esrc, N);

    // h0 = relu(x@W1+b1), inv0
    int g1blocks = 2048;   // 8192 waves = 8/SIMD: enough to stream 205 MB of x
    gemm1_kernel<<<g1blocks, 256, 0, stream>>>(x, W1, b1, h0, inv0, N, g1blocks * 4);

    // two attention layers: one wave per node
    int aggBlocks = (N + 3) / 4;   // 4 waves (nodes) per 256-thread block
    agg_kernel<<<aggBlocks, 256, 0, stream>>>(h0, inv0, esrc, rowstart, counts, beta1,
                                              h1, inv1, N);
    agg_kernel<<<aggBlocks, 256, 0, stream>>>(h1, inv1, esrc, rowstart, counts, beta2,
                                              h2, inv2, N);

    // out = log_softmax(h2@W2+b2)
    out_kernel<<<(N * 64 + 255) / 256, 256, 0, stream>>>(h2, W2, b2, out, N);
}